// Round 2
// baseline (191.913 us; speedup 1.0000x reference)
//
#include <hip/hip_runtime.h>
#include <hip/hip_fp16.h>

typedef _Float16 f16x2 __attribute__((ext_vector_type(2)));
typedef _Float16 f16x8 __attribute__((ext_vector_type(8)));
typedef float    f32x4 __attribute__((ext_vector_type(4)));

#define M_DIM   32
#define K_DIM   8192
#define N_DIM   28672
#define KWORDS  1024          // K/8 packed words per weight row
#define NKB     128           // K/64 scale blocks per row
#define NSPLIT  16            // K splits (combined via atomicAdd)
#define KCHUNK  512           // K per block (K/NSPLIT)
#define W32C    64            // packed words per chunk
#define NBLK_N  224           // N/128 n-blocks

// out[m,n] = bias[n]; atomicAdd accumulates the 16 K-split partials on top.
__global__ __launch_bounds__(256) void wql_init(const float* __restrict__ bias,
                                                float* __restrict__ out) {
    int n = blockIdx.x * 256 + threadIdx.x;
    int m = blockIdx.y;
    out[(size_t)m * N_DIM + n] = bias[n];
}

__device__ __forceinline__ unsigned pkrtz(float a, float b) {
    return __builtin_bit_cast(unsigned, __builtin_amdgcn_cvt_pkrtz(a, b));
}

// 8 nibbles of one packed word -> 8 fp16 dequantized weights.
// Pair p = nibbles (p, p+4): 0x6400|q == 1024+q exact; cpk = -(1024+8+zq);
// w = ((1024+q)+c)*s = (q-8-zq)*s. k-order within word: (0,4),(1,5),(2,6),(3,7)
// -- x staging uses the identical pairing, so the MFMA k-sum matches.
__device__ __forceinline__ f16x8 dq_word(unsigned W, f16x2 spk, f16x2 cpk) {
    union { f16x2 h[4]; f16x8 v; } r;
#pragma unroll
    for (int p = 0; p < 4; ++p) {
        unsigned raw = ((W >> (4 * p)) & 0x000F000Fu) | 0x64006400u;
        f16x2 f = __builtin_bit_cast(f16x2, raw);
        r.h[p] = (f + cpk) * spk;
    }
    return r.v;
}

// Block: 512 thr (8 waves), n-tile 128 (16 n per wave), full M=32.
// Stage x chunk to LDS once (32 KB, 1 barrier), then a fully-unrolled
// barrier-free K loop: 4 superblocks x 4 MFMA-k-steps. All global loads
// (4x uint4 qweight, 4 scales, 1 qzeros word) hoisted before the barrier.
__global__ __launch_bounds__(512, 4) void wql_main(
    const float* __restrict__ x, const unsigned* __restrict__ qw,
    const float* __restrict__ scales, const int* __restrict__ qzeros,
    float* __restrict__ out)
{
    // [32 rows][64 slots] of 16B (8 fp16). Swizzle: slot -> (w&48)|((w^row)&15)
    __shared__ uint4 xs[2048];

    const int tid  = threadIdx.x;
    const int bid  = blockIdx.x;
    const int nblk = bid % NBLK_N;     // split-blocks of one n-tile share bid%8 -> same XCD
    const int ks   = bid / NBLK_N;
    const int n0   = nblk * 128;

    const int wv   = tid >> 6;
    const int lane = tid & 63;
    const int g    = (lane >> 4) & 3;
    const int lr   = lane & 15;
    const int gh   = g >> 1;

    const int n_row = n0 + wv * 16 + lr;

    // ---- stage x[32][KCHUNK] -> LDS fp16, pair-permuted, swizzled ----
    {
        const int mt = tid >> 4;       // x row 0..31
        const int ws = tid & 15;
        const float* xp = x + (size_t)mt * K_DIM + ks * KCHUNK;
#pragma unroll
        for (int i = 0; i < 4; ++i) {
            int w = 16 * i + ws;
            float4 ra = ((const float4*)(xp + w * 8))[0];
            float4 rb = ((const float4*)(xp + w * 8))[1];
            uint4 v = { pkrtz(ra.x, rb.x), pkrtz(ra.y, rb.y),
                        pkrtz(ra.z, rb.z), pkrtz(ra.w, rb.w) };
            xs[mt * 64 + (w & 48) + ((w ^ mt) & 15)] = v;
        }
    }

    // ---- hoisted global loads (cover the whole K range of this block) ----
    // superblock sb (128 k = 16 words): lane g owns words 16sb+4g..+3 (one uint4);
    // those 4 words sit in scale block 2sb+gh, so one scale/zp per lane per sb.
    const float* srow = scales + (size_t)n_row * NKB + ks * 8;
    const float s0 = srow[gh];
    const float s1 = srow[gh + 2];
    const float s2 = srow[gh + 4];
    const float s3 = srow[gh + 6];
    const unsigned zw = ((const unsigned*)qzeros)[(size_t)n_row * (NKB / 8) + ks];

    const uint4* qp = (const uint4*)(qw + (size_t)n_row * KWORDS + ks * W32C);
    const uint4 wq0 = qp[g];
    const uint4 wq1 = qp[4 + g];
    const uint4 wq2 = qp[8 + g];
    const uint4 wq3 = qp[12 + g];

    __syncthreads();

    f32x4 acc0 = {0.f, 0.f, 0.f, 0.f};
    f32x4 acc1 = {0.f, 0.f, 0.f, 0.f};

#define SB(sb, wqv, sf)                                                        \
    {                                                                          \
        const int zq = (zw >> (4 * (2 * (sb) + gh))) & 0xF;                    \
        const _Float16 sh = (_Float16)(sf);                                    \
        const _Float16 ch = (_Float16)(-(float)(1032 + zq));                   \
        const f16x2 spk = { sh, sh };                                          \
        const f16x2 cpk = { ch, ch };                                          \
        const unsigned wa[4] = { wqv.x, wqv.y, wqv.z, wqv.w };                 \
        _Pragma("unroll")                                                      \
        for (int j = 0; j < 4; ++j) {                                          \
            f16x8 a = dq_word(wa[j], spk, cpk);                                \
            const int w = 16 * (sb) + 4 * g + j;                               \
            f16x8 b0 = __builtin_bit_cast(f16x8,                               \
                xs[lr * 64        + (w & 48) + ((w ^ lr) & 15)]);              \
            f16x8 b1 = __builtin_bit_cast(f16x8,                               \
                xs[(lr + 16) * 64 + (w & 48) + ((w ^ lr) & 15)]);              \
            acc0 = __builtin_amdgcn_mfma_f32_16x16x32_f16(a, b0, acc0, 0, 0, 0); \
            acc1 = __builtin_amdgcn_mfma_f32_16x16x32_f16(a, b1, acc1, 0, 0, 0); \
        }                                                                      \
    }

    SB(0, wq0, s0)
    SB(1, wq1, s1)
    SB(2, wq2, s2)
    SB(3, wq3, s3)
#undef SB

    // C/D: col(m) = lane&15, n-within-16-tile = 4*(lane>>4)+reg
    float* o0 = out + (size_t)lr * N_DIM        + n0 + wv * 16 + 4 * g;
    float* o1 = out + (size_t)(lr + 16) * N_DIM + n0 + wv * 16 + 4 * g;
#pragma unroll
    for (int r = 0; r < 4; ++r) {
        atomicAdd(o0 + r, acc0[r]);
        atomicAdd(o1 + r, acc1[r]);
    }
}

extern "C" void kernel_launch(void* const* d_in, const int* in_sizes, int n_in,
                              void* d_out, int out_size, void* d_ws, size_t ws_size,
                              hipStream_t stream) {
    const float*    x      = (const float*)d_in[0];
    const unsigned* qwght  = (const unsigned*)d_in[1];
    const float*    scales = (const float*)d_in[2];
    const int*      qzeros = (const int*)d_in[3];
    const float*    bias   = (const float*)d_in[4];
    float* out = (float*)d_out;

    wql_init<<<dim3(N_DIM / 256, M_DIM), 256, 0, stream>>>(bias, out);
    wql_main<<<dim3(NBLK_N * NSPLIT), 512, 0, stream>>>(x, qwght, scales, qzeros, out);
}

// Round 4
// 49.548 us; speedup vs baseline: 3.8733x; 3.8733x over previous
//
#include <hip/hip_runtime.h>
#include <hip/hip_fp16.h>

typedef _Float16 f16x2 __attribute__((ext_vector_type(2)));
typedef _Float16 f16x8 __attribute__((ext_vector_type(8)));
typedef float    f32x4 __attribute__((ext_vector_type(4)));

#define M_DIM   32
#define K_DIM   8192
#define N_DIM   28672
#define KWORDS  1024           // K/8 packed words per weight row
#define NKB     128            // K/64 scale blocks per row
#define NBLK_N  224            // N/128 n-blocks
#define OUT_ELEMS (M_DIM * N_DIM)

// ---- atomic-fallback init: out[m,n] = bias[n] ----
__global__ __launch_bounds__(256) void wql_init(const float* __restrict__ bias,
                                                float* __restrict__ out) {
    int n = blockIdx.x * 256 + threadIdx.x;
    int m = blockIdx.y;
    out[(size_t)m * N_DIM + n] = bias[n];
}

__device__ __forceinline__ unsigned pkrtz(float a, float b) {
    return __builtin_bit_cast(unsigned, __builtin_amdgcn_cvt_pkrtz(a, b));
}

// 8 nibbles -> 8 dequantized fp16. Pair p = nibbles (p,p+4); 0x6400|q = 1024+q
// exact; cpk = -(1024+8+zq); w = (q-8-zq)*s. k-perm (0,4),(1,5),(2,6),(3,7)
// is applied identically to the x staging, so the MFMA k-sum is unchanged.
__device__ __forceinline__ f16x8 dq_word(unsigned W, f16x2 spk, f16x2 cpk) {
    union { f16x2 h[4]; f16x8 v; } r;
#pragma unroll
    for (int p = 0; p < 4; ++p) {
        unsigned raw = ((W >> (4 * p)) & 0x000F000Fu) | 0x64006400u;
        f16x2 f = __builtin_bit_cast(f16x2, raw);
        r.h[p] = (f + cpk) * spk;
    }
    return r.v;
}

// NSB = number of 128-k superblocks per block (KCHUNK = NSB*128).
// Block: 512 thr / 8 waves, n-tile 128 (16 n per wave), all of M=32.
// All global loads hoisted (qw -> scales -> zeros -> x), 1 barrier, unrolled
// barrier-free compute, partials to ws (no atomics) or atomicAdd fallback.
template <int NSB, int MINW, bool ATOMIC>
__global__ __launch_bounds__(512, MINW) void wql_main(
    const float* __restrict__ x, const unsigned* __restrict__ qw,
    const float* __restrict__ scales, const unsigned* __restrict__ qzeros,
    float* __restrict__ outp)
{
    // [NSB sections][32 m][16 slots] of uint4; slot = word ^ (m&15)
    // (R1-measured conflict-free pattern).
    __shared__ uint4 xs[NSB * 512];

    const int tid  = threadIdx.x;
    const int bid  = blockIdx.x;
    const int nblk = bid % NBLK_N;
    const int ks   = bid / NBLK_N;
    const int n0   = nblk * 128;
    const int k0   = ks * (NSB * 128);

    const int wv   = tid >> 6;
    const int lane = tid & 63;
    const int g    = (lane >> 4) & 3;
    const int lr   = lane & 15;
    const int gh   = g >> 1;
    const int n_row = n0 + wv * 16 + lr;

    // ---- hoisted qweight stream: lane g owns uint4 (words 4g..4g+3) per section
    uint4 wq[NSB];
    const uint4* qp = (const uint4*)(qw + (size_t)n_row * KWORDS + (k0 >> 3));
#pragma unroll
    for (int s = 0; s < NSB; ++s) wq[s] = qp[4 * s + g];

    // ---- scales: NSB*2 floats per row, as f32x4 vectors
    f32x4 s4[NSB / 2];
    const f32x4* srow = (const f32x4*)(scales + (size_t)n_row * NKB + (k0 >> 6));
#pragma unroll
    for (int i = 0; i < NSB / 2; ++i) s4[i] = srow[i];

    // ---- zeros: NSB*2 nibbles per row; word offset = (k0/64)/8 = k0>>9
    unsigned zwv[NSB / 4];
    const unsigned* zrow = qzeros + (size_t)n_row * (NKB / 8) + (k0 >> 9);
    if constexpr (NSB == 8) {
        uint2 z = *(const uint2*)zrow; zwv[0] = z.x; zwv[1] = z.y;
    } else {
        uint4 z = *(const uint4*)zrow; zwv[0] = z.x; zwv[1] = z.y; zwv[2] = z.z; zwv[3] = z.w;
    }

    // ---- stage x -> LDS fp16 (pair-permuted), in groups of 4 sections
    {
        const int mt  = tid >> 4;      // x row 0..31
        const int wsl = tid & 15;      // word slot within section
        const float* xp = x + (size_t)mt * K_DIM + k0 + wsl * 8;
        const int xoff  = mt * 16 + (wsl ^ (mt & 15));
#pragma unroll
        for (int grp = 0; grp < NSB / 4; ++grp) {
            float4 ra[4], rb[4];
#pragma unroll
            for (int i = 0; i < 4; ++i) {
                const float4* p = (const float4*)(xp + (grp * 4 + i) * 128);
                ra[i] = p[0]; rb[i] = p[1];
            }
#pragma unroll
            for (int i = 0; i < 4; ++i) {
                uint4 v = { pkrtz(ra[i].x, rb[i].x), pkrtz(ra[i].y, rb[i].y),
                            pkrtz(ra[i].z, rb[i].z), pkrtz(ra[i].w, rb[i].w) };
                xs[(grp * 4 + i) * 512 + xoff] = v;
            }
        }
    }
    __syncthreads();

    f32x4 acc0 = {0.f, 0.f, 0.f, 0.f};
    f32x4 acc1 = {0.f, 0.f, 0.f, 0.f};

#pragma unroll
    for (int sb = 0; sb < NSB; ++sb) {
        // scale block within chunk = 2*sb + gh; nibble (2sb+gh)&7 of word
        // (2sb)>>3 (2sb even -> gh never crosses a word boundary)
        const int zq = (zwv[(2 * sb) >> 3] >> (4 * ((2 * sb + gh) & 7))) & 0xF;
        const float sf = gh ? s4[sb >> 1][(sb & 1) * 2 + 1]
                            : s4[sb >> 1][(sb & 1) * 2];
        const _Float16 sh = (_Float16)sf;
        const _Float16 ch = (_Float16)(-(float)(1032 + zq));
        const f16x2 spk = { sh, sh };
        const f16x2 cpk = { ch, ch };
        const unsigned wa[4] = { wq[sb].x, wq[sb].y, wq[sb].z, wq[sb].w };
#pragma unroll
        for (int j = 0; j < 4; ++j) {
            f16x8 a = dq_word(wa[j], spk, cpk);
            const int w = 4 * g + j;
            f16x8 b0 = __builtin_bit_cast(f16x8, xs[sb * 512 + lr * 16        + (w ^ lr)]);
            f16x8 b1 = __builtin_bit_cast(f16x8, xs[sb * 512 + (lr + 16) * 16 + (w ^ lr)]);
            acc0 = __builtin_amdgcn_mfma_f32_16x16x32_f16(a, b0, acc0, 0, 0, 0);
            acc1 = __builtin_amdgcn_mfma_f32_16x16x32_f16(a, b1, acc1, 0, 0, 0);
        }
    }

    // C/D: col(m) = lane&15, n-within-16 = 4*(lane>>4)+reg
    const size_t obase = (size_t)lr * N_DIM + n0 + wv * 16 + 4 * g;
    if constexpr (ATOMIC) {
#pragma unroll
        for (int r = 0; r < 4; ++r) {
            atomicAdd(outp + obase + r, acc0[r]);
            atomicAdd(outp + obase + (size_t)16 * N_DIM + r, acc1[r]);
        }
    } else {
        float* dst = outp + (size_t)ks * OUT_ELEMS;
        *(f32x4*)(dst + obase) = acc0;
        *(f32x4*)(dst + obase + (size_t)16 * N_DIM) = acc1;
    }
}

// out = bias + sum of 8 split partials (ws path)
__global__ __launch_bounds__(256) void wql_reduce(const float* __restrict__ ws,
                                                  const float* __restrict__ bias,
                                                  float* __restrict__ out) {
    const int i4 = (blockIdx.x * 256 + threadIdx.x) * 4;
    const int n  = i4 % N_DIM;
    f32x4 acc = *(const f32x4*)(bias + n);
#pragma unroll
    for (int s = 0; s < 8; ++s)
        acc += *(const f32x4*)(ws + (size_t)s * OUT_ELEMS + i4);
    *(f32x4*)(out + i4) = acc;
}

extern "C" void kernel_launch(void* const* d_in, const int* in_sizes, int n_in,
                              void* d_out, int out_size, void* d_ws, size_t ws_size,
                              hipStream_t stream) {
    const float*    x      = (const float*)d_in[0];
    const unsigned* qwght  = (const unsigned*)d_in[1];
    const float*    scales = (const float*)d_in[2];
    const unsigned* qzeros = (const unsigned*)d_in[3];
    const float*    bias   = (const float*)d_in[4];
    float* out = (float*)d_out;

    const size_t need = (size_t)8 * OUT_ELEMS * sizeof(float);  // 29.4 MB
    if (ws_size >= need) {
        // split partials -> ws (no atomics), then reduce
        wql_main<8, 4, false><<<dim3(NBLK_N * 8), 512, 0, stream>>>(
            x, qwght, scales, qzeros, (float*)d_ws);
        wql_reduce<<<dim3(OUT_ELEMS / 1024), 256, 0, stream>>>(
            (const float*)d_ws, bias, out);
    } else {
        // fallback: 4-way split with atomics onto bias-initialized out
        wql_init<<<dim3(N_DIM / 256, M_DIM), 256, 0, stream>>>(bias, out);
        wql_main<16, 2, true><<<dim3(NBLK_N * 4), 512, 0, stream>>>(
            x, qwght, scales, qzeros, out);
    }
}